// Round 3
// baseline (443.014 us; speedup 1.0000x reference)
//
#include <hip/hip_runtime.h>
#include <hip/hip_bf16.h>
#include <hip/hip_cooperative_groups.h>

namespace cg = cooperative_groups;

#define BATCH 32
#define NN 4096
#define KK 32
#define GRID 512

typedef __attribute__((ext_vector_type(8))) short bf16x8;
typedef __attribute__((ext_vector_type(4))) float f32x4;

// ws layout (float offsets)
#define WS_PART   0          // 32*16*256 = 131072 (dead after stage B)
#define WS_SMP    0          // 5*131072 = 655360 (written by stage F)
#define WS_MEANS  655360     // 8192
#define WS_WCOMB  663552     // 65536
#define WS_KP     729088     // 262144
#define WS_G      991232     // 131072 floats = 262144 bf16

__device__ __forceinline__ unsigned int pk2(float lo, float hi) {
  union { __hip_bfloat162 b; unsigned int u; } c;
  c.b = __float22bfloat162_rn(float2{lo, hi});   // -> v_cvt_pk_bf16_f32 (RTNE)
  return c.u;
}

__device__ __forceinline__ unsigned short f2bf(float x) {
  unsigned int u = __float_as_uint(x);
  u += 0x7fffu + ((u >> 16) & 1u);
  return (unsigned short)(u >> 16);
}

// ==================== cooperative mega-kernel ====================
__global__ __launch_bounds__(256, 2) void mega(
    const float* __restrict__ h, const float* __restrict__ pos,
    const float* __restrict__ Wsrc, const float* __restrict__ Wdst,
    const float* __restrict__ Wkp, const float* __restrict__ bkp,
    const float* __restrict__ gamma, const float* __restrict__ beta,
    float* __restrict__ out, float* __restrict__ ws) {
  cg::grid_group grid = cg::this_grid();
  const int bk = blockIdx.x;
  const int t = threadIdx.x;
  const float LOG2E = 1.4426950408889634f;
  __shared__ float4 sm4[256];

  // ---- Stage A: zero d_out + partial column sums of h ----
  {
    int idx = bk * 256 + t;
    if (idx < 78592) ((float4*)out)[idx] = float4{0.f, 0.f, 0.f, 0.f};
    int b = bk >> 4, p = bk & 15;
    int c4 = t & 63, rg = t >> 6;
    const float4* hp = (const float4*)h + (((size_t)(b * NN + p * 256)) << 6) + c4;
    float4 acc = {0.f, 0.f, 0.f, 0.f};
    for (int r = rg; r < 256; r += 4) {
      float4 v = hp[(size_t)r << 6];
      acc.x += v.x; acc.y += v.y; acc.z += v.z; acc.w += v.w;
    }
    sm4[t] = acc;
    __syncthreads();
    if (t < 64) {
      float4 a = sm4[t], b2 = sm4[t + 64], c = sm4[t + 128], d = sm4[t + 192];
      float4 tot = {a.x + b2.x + c.x + d.x, a.y + b2.y + c.y + d.y,
                    a.z + b2.z + c.z + d.z, a.w + b2.w + c.w + d.w};
      ((float4*)(ws + WS_PART))[(size_t)(b * 16 + p) * 64 + t] = tot;
    }
    __syncthreads();
  }
  grid.sync();

  // ---- Stage B: means (blocks 0..31) + wcomb = Wdst^T@Wsrc (blocks 32..287) ----
  if (bk < 32) {
    float s = 0.f;
#pragma unroll
    for (int p = 0; p < 16; p++) s += ws[WS_PART + (size_t)(bk * 16 + p) * 256 + t];
    ws[WS_MEANS + bk * 256 + t] = s * (1.0f / NN);
  } else if (bk < 288) {
    int dp = bk - 32;
    float acc = 0.f;
#pragma unroll 8
    for (int e = 0; e < 256; e++) acc += Wdst[e * 256 + dp] * Wsrc[e * 256 + t];
    ws[WS_WCOMB + dp * 256 + t] = acc;
  }
  grid.sync();

  // ---- Stage C: kp = silu(mean @ Wkp^T + b) (blocks 0..255) ----
  if (bk < 256) {
    int jt = bk & 31, bg = bk >> 5;
    int j = jt * 256 + t, b0 = bg * 4;
    const float4* wp = (const float4*)Wkp + (size_t)j * 64;
    float acc[4] = {0.f, 0.f, 0.f, 0.f};
    for (int d4 = 0; d4 < 64; d4++) {
      float4 w = wp[d4];
#pragma unroll
      for (int i = 0; i < 4; i++) {
        float4 m = ((const float4*)(ws + WS_MEANS + (size_t)(b0 + i) * 256))[d4];
        acc[i] += m.x * w.x + m.y * w.y + m.z * w.z + m.w * w.w;
      }
    }
    float bb = bkp[j];
#pragma unroll
    for (int i = 0; i < 4; i++) {
      float x = acc[i] + bb;
      ws[WS_KP + (size_t)(b0 + i) * 8192 + j] = x / (1.0f + __expf(-x));
    }
  }
  grid.sync();

  // ---- Stage D: LayerNorm over 8192, in place (blocks 0..31) ----
  if (bk < 32) {
    float* kp = ws + WS_KP + (size_t)bk * 8192;
    float v[32];
    float s = 0.f, sq = 0.f;
#pragma unroll
    for (int i = 0; i < 32; i++) {
      v[i] = kp[i * 256 + t];
      s += v[i]; sq += v[i] * v[i];
    }
#pragma unroll
    for (int o = 1; o < 64; o <<= 1) { s += __shfl_xor(s, o); sq += __shfl_xor(sq, o); }
    float* smf = (float*)sm4;
    int w = t >> 6, lane = t & 63;
    if (lane == 0) { smf[w] = s; smf[8 + w] = sq; }
    __syncthreads();
    float S = smf[0] + smf[1] + smf[2] + smf[3];
    float SQ = smf[8] + smf[9] + smf[10] + smf[11];
    float mu = S * (1.0f / 8192.0f);
    float var = fmaxf(SQ * (1.0f / 8192.0f) - mu * mu, 0.f);
    float rs = rsqrtf(var + 1e-5f);
#pragma unroll
    for (int i = 0; i < 32; i++) {
      int j = i * 256 + t;
      kp[j] = (v[i] - mu) * rs * gamma[j] + beta[j];
    }
  }
  grid.sync();

  // ---- Stage E: g = (kp_norm @ wcomb) / 16 -> bf16 (blocks 0..127) ----
  if (bk < 128) {
    int dc = bk & 3, b = bk >> 2;
    int d = dc * 64 + (t & 63);
    int kb = t >> 6;
    const float* kpn = ws + WS_KP;
    const float* wcomb = ws + WS_WCOMB;
    unsigned short* g = (unsigned short*)(ws + WS_G);
    float acc[8] = {0.f, 0.f, 0.f, 0.f, 0.f, 0.f, 0.f, 0.f};
    for (int dp4 = 0; dp4 < 64; dp4++) {
      float w0 = wcomb[(dp4 * 4 + 0) * 256 + d];
      float w1 = wcomb[(dp4 * 4 + 1) * 256 + d];
      float w2 = wcomb[(dp4 * 4 + 2) * 256 + d];
      float w3 = wcomb[(dp4 * 4 + 3) * 256 + d];
#pragma unroll
      for (int i = 0; i < 8; i++) {
        int k = kb + i * 4;
        float4 kv = ((const float4*)(kpn + (size_t)b * 8192 + k * 256))[dp4];
        acc[i] += kv.x * w0 + kv.y * w1 + kv.z * w2 + kv.w * w3;
      }
    }
#pragma unroll
    for (int i = 0; i < 8; i++) {
      int k = kb + i * 4;
      g[(size_t)(b * KK + k) * 256 + d] = f2bf(acc[i] * 0.0625f);
    }
  }
  grid.sync();

  // ---- Stage F: attention partials (each block: 2 (s,b) pairs) ----
  {
    int lane = t & 63, w = t >> 6;
    int l15 = lane & 15, l4 = lane >> 4;
    const unsigned short* gall = (const unsigned short*)(ws + WS_G);
    for (int p = 0; p < 2; p++) {
      int pair = bk + 512 * p;
      int s = pair & 31, b = pair >> 5;
      const unsigned short* gb = gall + (size_t)b * 8192;
      bf16x8 gf0[8], gf1[8];
#pragma unroll
      for (int kd = 0; kd < 8; kd++) {
        gf0[kd] = *(const bf16x8*)(gb + ((size_t)l15 << 8) + kd * 32 + (l4 << 3));
        gf1[kd] = *(const bf16x8*)(gb + ((size_t)(16 + l15) << 8) + kd * 32 + (l4 << 3));
      }
      float m0 = -3.0e38f, m1 = -3.0e38f;
      float L0 = 0.f, L1 = 0.f;
      float P0x = 0.f, P0y = 0.f, P0z = 0.f, P1x = 0.f, P1y = 0.f, P1z = 0.f;
      for (int tile = 0; tile < 2; tile++) {
        int nbase = s * 128 + tile * 64 + w * 16;
        int rowA = nbase + l15;
        const float4* hp = (const float4*)(h + ((size_t)(b * NN + rowA) << 8));
        int co = l4 * 2;
        f32x4 acc0 = {0.f, 0.f, 0.f, 0.f}, acc1 = {0.f, 0.f, 0.f, 0.f};
#pragma unroll
        for (int kd = 0; kd < 8; kd++) {
          float4 v0 = hp[kd * 8 + co];
          float4 v1 = hp[kd * 8 + co + 1];
          union { unsigned int u[4]; bf16x8 v; } au;
          au.u[0] = pk2(v0.x, v0.y); au.u[1] = pk2(v0.z, v0.w);
          au.u[2] = pk2(v1.x, v1.y); au.u[3] = pk2(v1.z, v1.w);
          acc0 = __builtin_amdgcn_mfma_f32_16x16x32_bf16(au.v, gf0[kd], acc0, 0, 0, 0);
          acc1 = __builtin_amdgcn_mfma_f32_16x16x32_bf16(au.v, gf1[kd], acc1, 0, 0, 0);
        }
        float px[4], py[4], pz[4];
#pragma unroll
        for (int j = 0; j < 4; j++) {
          const float* pp = pos + (size_t)(b * NN + nbase + l4 * 4 + j) * 3;
          px[j] = pp[0]; py[j] = pp[1]; pz[j] = pp[2];
        }
        {
          float tm = fmaxf(fmaxf(acc0[0], acc0[1]), fmaxf(acc0[2], acc0[3]));
          tm = fmaxf(tm, __shfl_xor(tm, 16));
          tm = fmaxf(tm, __shfl_xor(tm, 32));
          float mn = fmaxf(m0, tm);
          float corr = exp2f((m0 - mn) * LOG2E);
          float e0 = exp2f((acc0[0] - mn) * LOG2E);
          float e1 = exp2f((acc0[1] - mn) * LOG2E);
          float e2 = exp2f((acc0[2] - mn) * LOG2E);
          float e3 = exp2f((acc0[3] - mn) * LOG2E);
          float se = e0 + e1 + e2 + e3;
          float sx = e0 * px[0] + e1 * px[1] + e2 * px[2] + e3 * px[3];
          float sy = e0 * py[0] + e1 * py[1] + e2 * py[2] + e3 * py[3];
          float sz = e0 * pz[0] + e1 * pz[1] + e2 * pz[2] + e3 * pz[3];
          se += __shfl_xor(se, 16); se += __shfl_xor(se, 32);
          sx += __shfl_xor(sx, 16); sx += __shfl_xor(sx, 32);
          sy += __shfl_xor(sy, 16); sy += __shfl_xor(sy, 32);
          sz += __shfl_xor(sz, 16); sz += __shfl_xor(sz, 32);
          L0 = L0 * corr + se; P0x = P0x * corr + sx;
          P0y = P0y * corr + sy; P0z = P0z * corr + sz; m0 = mn;
        }
        {
          float tm = fmaxf(fmaxf(acc1[0], acc1[1]), fmaxf(acc1[2], acc1[3]));
          tm = fmaxf(tm, __shfl_xor(tm, 16));
          tm = fmaxf(tm, __shfl_xor(tm, 32));
          float mn = fmaxf(m1, tm);
          float corr = exp2f((m1 - mn) * LOG2E);
          float e0 = exp2f((acc1[0] - mn) * LOG2E);
          float e1 = exp2f((acc1[1] - mn) * LOG2E);
          float e2 = exp2f((acc1[2] - mn) * LOG2E);
          float e3 = exp2f((acc1[3] - mn) * LOG2E);
          float se = e0 + e1 + e2 + e3;
          float sx = e0 * px[0] + e1 * px[1] + e2 * px[2] + e3 * px[3];
          float sy = e0 * py[0] + e1 * py[1] + e2 * py[2] + e3 * py[3];
          float sz = e0 * pz[0] + e1 * pz[1] + e2 * pz[2] + e3 * pz[3];
          se += __shfl_xor(se, 16); se += __shfl_xor(se, 32);
          sx += __shfl_xor(sx, 16); sx += __shfl_xor(sx, 32);
          sy += __shfl_xor(sy, 16); sy += __shfl_xor(sy, 32);
          sz += __shfl_xor(sz, 16); sz += __shfl_xor(sz, 32);
          L1 = L1 * corr + se; P1x = P1x * corr + sx;
          P1y = P1y * corr + sy; P1z = P1z * corr + sz; m1 = mn;
        }
      }
      if (lane < 32) {
        int kt = lane >> 4;
        float mv = kt ? m1 : m0;
        float lv = kt ? L1 : L0;
        float pxv = kt ? P1x : P0x;
        float pyv = kt ? P1y : P0y;
        float pzv = kt ? P1z : P0z;
        size_t base = ((size_t)(b * KK + lane)) * 128 + s * 4 + w;
        ws[WS_SMP + base] = mv;
        ws[WS_SMP + 131072 + base] = lv;
        ws[WS_SMP + 262144 + base] = pxv;
        ws[WS_SMP + 393216 + base] = pyv;
        ws[WS_SMP + 524288 + base] = pzv;
      }
    }
  }
  grid.sync();

  // ---- Stage G: combine partials -> kp_pos (one wave per (b,k)) ----
  {
    int w = t >> 6, lane = t & 63;
    int gw = bk * 4 + w;
    if (gw < 1024) {
      size_t i0 = (size_t)gw * 128 + 2 * lane;
      float mA = ws[WS_SMP + i0], mB = ws[WS_SMP + i0 + 1];
      float M = fmaxf(mA, mB);
#pragma unroll
      for (int o = 1; o < 64; o <<= 1) M = fmaxf(M, __shfl_xor(M, o));
      float fA = exp2f((mA - M) * LOG2E), fB = exp2f((mB - M) * LOG2E);
      float L = ws[WS_SMP + 131072 + i0] * fA + ws[WS_SMP + 131072 + i0 + 1] * fB;
      float X = ws[WS_SMP + 262144 + i0] * fA + ws[WS_SMP + 262144 + i0 + 1] * fB;
      float Y = ws[WS_SMP + 393216 + i0] * fA + ws[WS_SMP + 393216 + i0 + 1] * fB;
      float Z = ws[WS_SMP + 524288 + i0] * fA + ws[WS_SMP + 524288 + i0 + 1] * fB;
#pragma unroll
      for (int o = 1; o < 64; o <<= 1) {
        L += __shfl_xor(L, o); X += __shfl_xor(X, o);
        Y += __shfl_xor(Y, o); Z += __shfl_xor(Z, o);
      }
      if (lane == 0) {
        float inv = 1.0f / L;
        out[gw * 3 + 0] = X * inv;
        out[gw * 3 + 1] = Y * inv;
        out[gw * 3 + 2] = Z * inv;
      }
    }
  }
}

// ==================== fallback: round-2 8-kernel chain ====================
__global__ void kzero(float4* __restrict__ out, int n4) {
  int i = blockIdx.x * 256 + threadIdx.x;
  if (i < n4) out[i] = float4{0.f, 0.f, 0.f, 0.f};
}

__global__ void k0_partial(const float* __restrict__ h, float* __restrict__ part) {
  int p = blockIdx.x, b = blockIdx.y;
  int t = threadIdx.x;
  int c4 = t & 63, rg = t >> 6;
  const float4* hp = (const float4*)h + (size_t)(b * NN + p * 128) * 64 + c4;
  float4 acc = {0.f, 0.f, 0.f, 0.f};
  for (int r = rg; r < 128; r += 4) {
    float4 v = hp[(size_t)r * 64];
    acc.x += v.x; acc.y += v.y; acc.z += v.z; acc.w += v.w;
  }
  __shared__ float4 sm[256];
  sm[t] = acc;
  __syncthreads();
  if (t < 64) {
    float4 a = sm[t], b2 = sm[t + 64], c = sm[t + 128], d = sm[t + 192];
    float4 tot = {a.x + b2.x + c.x + d.x, a.y + b2.y + c.y + d.y,
                  a.z + b2.z + c.z + d.z, a.w + b2.w + c.w + d.w};
    ((float4*)part)[(size_t)(b * 32 + p) * 64 + t] = tot;
  }
}

__global__ void k1_mean_wcomb(const float* __restrict__ part,
                              const float* __restrict__ Wsrc,
                              const float* __restrict__ Wdst,
                              float* __restrict__ means,
                              float* __restrict__ wcomb) {
  int bid = blockIdx.x, t = threadIdx.x;
  if (bid < 256) {
    int dp = bid;
    float acc = 0.f;
#pragma unroll 4
    for (int e = 0; e < 256; e++) acc += Wdst[e * 256 + dp] * Wsrc[e * 256 + t];
    wcomb[dp * 256 + t] = acc;
  } else {
    int b = bid - 256;
    float s = 0.f;
    for (int p = 0; p < 32; p++) s += part[(size_t)(b * 32 + p) * 256 + t];
    means[b * 256 + t] = s * (1.0f / NN);
  }
}

__global__ void k2a_kp(const float* __restrict__ means, const float* __restrict__ Wkp,
                       const float* __restrict__ bkp, float* __restrict__ kp) {
  int jt = blockIdx.x, bg = blockIdx.y, t = threadIdx.x;
  int j = jt * 256 + t, b0 = bg * 4;
  const float4* wp = (const float4*)Wkp + (size_t)j * 64;
  float acc[4] = {0.f, 0.f, 0.f, 0.f};
  for (int d4 = 0; d4 < 64; d4++) {
    float4 w = wp[d4];
#pragma unroll
    for (int i = 0; i < 4; i++) {
      float4 m = ((const float4*)(means + (size_t)(b0 + i) * 256))[d4];
      acc[i] += m.x * w.x + m.y * w.y + m.z * w.z + m.w * w.w;
    }
  }
  float bb = bkp[j];
#pragma unroll
  for (int i = 0; i < 4; i++) {
    float x = acc[i] + bb;
    kp[(size_t)(b0 + i) * 8192 + j] = x / (1.0f + __expf(-x));
  }
}

__global__ void k2b_ln(float* __restrict__ kp, const float* __restrict__ gamma,
                       const float* __restrict__ beta) {
  int b = blockIdx.x, t = threadIdx.x;
  float v[8];
  float s = 0.f, sq = 0.f;
#pragma unroll
  for (int i = 0; i < 8; i++) {
    v[i] = kp[(size_t)b * 8192 + t + i * 1024];
    s += v[i]; sq += v[i] * v[i];
  }
#pragma unroll
  for (int o = 1; o < 64; o <<= 1) { s += __shfl_xor(s, o); sq += __shfl_xor(sq, o); }
  __shared__ float ss[16], ssq[16];
  int w = t >> 6, lane = t & 63;
  if (lane == 0) { ss[w] = s; ssq[w] = sq; }
  __syncthreads();
  if (t == 0) {
    float a = 0.f, a2 = 0.f;
    for (int i = 0; i < 16; i++) { a += ss[i]; a2 += ssq[i]; }
    ss[0] = a; ssq[0] = a2;
  }
  __syncthreads();
  float mu = ss[0] * (1.0f / 8192.0f);
  float var = ssq[0] * (1.0f / 8192.0f) - mu * mu;
  var = fmaxf(var, 0.f);
  float rs = rsqrtf(var + 1e-5f);
#pragma unroll
  for (int i = 0; i < 8; i++) {
    int j = t + i * 1024;
    kp[(size_t)b * 8192 + j] = (v[i] - mu) * rs * gamma[j] + beta[j];
  }
}

__global__ void k2c_g(const float* __restrict__ kpn, const float* __restrict__ wcomb,
                      unsigned short* __restrict__ g) {
  int dc = blockIdx.x, b = blockIdx.y, t = threadIdx.x;
  int d = dc * 64 + (t & 63);
  int kb = t >> 6;
  float acc[8] = {0.f, 0.f, 0.f, 0.f, 0.f, 0.f, 0.f, 0.f};
  for (int dp4 = 0; dp4 < 64; dp4++) {
    float w0 = wcomb[(dp4 * 4 + 0) * 256 + d];
    float w1 = wcomb[(dp4 * 4 + 1) * 256 + d];
    float w2 = wcomb[(dp4 * 4 + 2) * 256 + d];
    float w3 = wcomb[(dp4 * 4 + 3) * 256 + d];
#pragma unroll
    for (int i = 0; i < 8; i++) {
      int k = kb + i * 4;
      float4 kv = ((const float4*)(kpn + (size_t)b * 8192 + k * 256))[dp4];
      acc[i] += kv.x * w0 + kv.y * w1 + kv.z * w2 + kv.w * w3;
    }
  }
#pragma unroll
  for (int i = 0; i < 8; i++) {
    int k = kb + i * 4;
    g[(size_t)(b * KK + k) * 256 + d] = f2bf(acc[i] * 0.0625f);
  }
}

__global__ __launch_bounds__(256, 2) void k3_attn(const float* __restrict__ h,
                                                  const float* __restrict__ pos,
                                                  const unsigned short* __restrict__ g,
                                                  float* __restrict__ smp) {
  int s = blockIdx.x, b = blockIdx.y;
  int t = threadIdx.x;
  int lane = t & 63, w = t >> 6;
  int l15 = lane & 15, l4 = lane >> 4;
  const float LOG2E = 1.4426950408889634f;
  const unsigned short* gb = g + (size_t)b * 8192;
  bf16x8 gf0[8], gf1[8];
#pragma unroll
  for (int kd = 0; kd < 8; kd++) {
    gf0[kd] = *(const bf16x8*)(gb + ((size_t)l15 << 8) + kd * 32 + (l4 << 3));
    gf1[kd] = *(const bf16x8*)(gb + ((size_t)(16 + l15) << 8) + kd * 32 + (l4 << 3));
  }
  float m0 = -3.0e38f, m1 = -3.0e38f;
  float L0 = 0.f, L1 = 0.f;
  float P0x = 0.f, P0y = 0.f, P0z = 0.f, P1x = 0.f, P1y = 0.f, P1z = 0.f;
  for (int tile = 0; tile < 2; tile++) {
    int nbase = s * 128 + tile * 64 + w * 16;
    int rowA = nbase + l15;
    const float4* hp = (const float4*)(h + ((size_t)(b * NN + rowA) << 8));
    int co = l4 * 2;
    f32x4 acc0 = {0.f, 0.f, 0.f, 0.f}, acc1 = {0.f, 0.f, 0.f, 0.f};
#pragma unroll
    for (int kd = 0; kd < 8; kd++) {
      float4 v0 = hp[kd * 8 + co];
      float4 v1 = hp[kd * 8 + co + 1];
      union { unsigned int u[4]; bf16x8 v; } au;
      au.u[0] = pk2(v0.x, v0.y); au.u[1] = pk2(v0.z, v0.w);
      au.u[2] = pk2(v1.x, v1.y); au.u[3] = pk2(v1.z, v1.w);
      acc0 = __builtin_amdgcn_mfma_f32_16x16x32_bf16(au.v, gf0[kd], acc0, 0, 0, 0);
      acc1 = __builtin_amdgcn_mfma_f32_16x16x32_bf16(au.v, gf1[kd], acc1, 0, 0, 0);
    }
    float px[4], py[4], pz[4];
#pragma unroll
    for (int j = 0; j < 4; j++) {
      const float* pp = pos + (size_t)(b * NN + nbase + l4 * 4 + j) * 3;
      px[j] = pp[0]; py[j] = pp[1]; pz[j] = pp[2];
    }
    {
      float tm = fmaxf(fmaxf(acc0[0], acc0[1]), fmaxf(acc0[2], acc0[3]));
      tm = fmaxf(tm, __shfl_xor(tm, 16));
      tm = fmaxf(tm, __shfl_xor(tm, 32));
      float mn = fmaxf(m0, tm);
      float corr = exp2f((m0 - mn) * LOG2E);
      float e0 = exp2f((acc0[0] - mn) * LOG2E);
      float e1 = exp2f((acc0[1] - mn) * LOG2E);
      float e2 = exp2f((acc0[2] - mn) * LOG2E);
      float e3 = exp2f((acc0[3] - mn) * LOG2E);
      float se = e0 + e1 + e2 + e3;
      float sx = e0 * px[0] + e1 * px[1] + e2 * px[2] + e3 * px[3];
      float sy = e0 * py[0] + e1 * py[1] + e2 * py[2] + e3 * py[3];
      float sz = e0 * pz[0] + e1 * pz[1] + e2 * pz[2] + e3 * pz[3];
      se += __shfl_xor(se, 16); se += __shfl_xor(se, 32);
      sx += __shfl_xor(sx, 16); sx += __shfl_xor(sx, 32);
      sy += __shfl_xor(sy, 16); sy += __shfl_xor(sy, 32);
      sz += __shfl_xor(sz, 16); sz += __shfl_xor(sz, 32);
      L0 = L0 * corr + se; P0x = P0x * corr + sx;
      P0y = P0y * corr + sy; P0z = P0z * corr + sz; m0 = mn;
    }
    {
      float tm = fmaxf(fmaxf(acc1[0], acc1[1]), fmaxf(acc1[2], acc1[3]));
      tm = fmaxf(tm, __shfl_xor(tm, 16));
      tm = fmaxf(tm, __shfl_xor(tm, 32));
      float mn = fmaxf(m1, tm);
      float corr = exp2f((m1 - mn) * LOG2E);
      float e0 = exp2f((acc1[0] - mn) * LOG2E);
      float e1 = exp2f((acc1[1] - mn) * LOG2E);
      float e2 = exp2f((acc1[2] - mn) * LOG2E);
      float e3 = exp2f((acc1[3] - mn) * LOG2E);
      float se = e0 + e1 + e2 + e3;
      float sx = e0 * px[0] + e1 * px[1] + e2 * px[2] + e3 * px[3];
      float sy = e0 * py[0] + e1 * py[1] + e2 * py[2] + e3 * py[3];
      float sz = e0 * pz[0] + e1 * pz[1] + e2 * pz[2] + e3 * pz[3];
      se += __shfl_xor(se, 16); se += __shfl_xor(se, 32);
      sx += __shfl_xor(sx, 16); sx += __shfl_xor(sx, 32);
      sy += __shfl_xor(sy, 16); sy += __shfl_xor(sy, 32);
      sz += __shfl_xor(sz, 16); sz += __shfl_xor(sz, 32);
      L1 = L1 * corr + se; P1x = P1x * corr + sx;
      P1y = P1y * corr + sy; P1z = P1z * corr + sz; m1 = mn;
    }
  }
  if (lane < 32) {
    int kt = lane >> 4;
    float mv = kt ? m1 : m0;
    float lv = kt ? L1 : L0;
    float pxv = kt ? P1x : P0x;
    float pyv = kt ? P1y : P0y;
    float pzv = kt ? P1z : P0z;
    size_t base = ((size_t)(b * KK + lane)) * 128 + s * 4 + w;
    smp[base] = mv;
    smp[131072 + base] = lv;
    smp[262144 + base] = pxv;
    smp[393216 + base] = pyv;
    smp[524288 + base] = pzv;
  }
}

__global__ void k4_final(const float* __restrict__ smp, float* __restrict__ out) {
  int id = blockIdx.x * 256 + threadIdx.x;
  if (id >= BATCH * KK) return;
  const float LOG2E = 1.4426950408889634f;
  size_t base = (size_t)id * 128;
  float M = -3.0e38f;
  for (int j = 0; j < 128; j++) M = fmaxf(M, smp[base + j]);
  float L = 0.f, X = 0.f, Y = 0.f, Z = 0.f;
  for (int j = 0; j < 128; j++) {
    float f = exp2f((smp[base + j] - M) * LOG2E);
    L += smp[131072 + base + j] * f;
    X += smp[262144 + base + j] * f;
    Y += smp[393216 + base + j] * f;
    Z += smp[524288 + base + j] * f;
  }
  float inv = 1.0f / L;
  out[id * 3 + 0] = X * inv;
  out[id * 3 + 1] = Y * inv;
  out[id * 3 + 2] = Z * inv;
}

extern "C" void kernel_launch(void* const* d_in, const int* in_sizes, int n_in,
                              void* d_out, int out_size, void* d_ws, size_t ws_size,
                              hipStream_t stream) {
  const float* h     = (const float*)d_in[0];
  const float* pos   = (const float*)d_in[1];
  const float* Wsrc  = (const float*)d_in[2];
  const float* Wdst  = (const float*)d_in[3];
  const float* Wkp   = (const float*)d_in[4];
  const float* bkp   = (const float*)d_in[5];
  const float* gamma = (const float*)d_in[6];
  const float* beta  = (const float*)d_in[7];
  float* out = (float*)d_out;
  float* ws  = (float*)d_ws;

  void* args[] = {(void*)&h, (void*)&pos, (void*)&Wsrc, (void*)&Wdst,
                  (void*)&Wkp, (void*)&bkp, (void*)&gamma, (void*)&beta,
                  (void*)&out, (void*)&ws};
  hipError_t err = hipLaunchCooperativeKernel((const void*)mega, dim3(GRID),
                                              dim3(256), args, 0, stream);
  if (err != hipSuccess) {
    // fallback: 8-kernel chain (round-2 structure, wider VGPR budget on k3)
    int n4 = out_size / 4;
    kzero<<<(n4 + 255) / 256, 256, 0, stream>>>((float4*)d_out, n4);
    k0_partial<<<dim3(32, BATCH), 256, 0, stream>>>(h, ws + 0);
    k1_mean_wcomb<<<288, 256, 0, stream>>>(ws + 0, Wsrc, Wdst,
                                           ws + WS_MEANS, ws + WS_WCOMB);
    k2a_kp<<<dim3(32, 8), 256, 0, stream>>>(ws + WS_MEANS, Wkp, bkp, ws + WS_KP);
    k2b_ln<<<BATCH, 1024, 0, stream>>>(ws + WS_KP, gamma, beta);
    k2c_g<<<dim3(4, BATCH), 256, 0, stream>>>(ws + WS_KP, ws + WS_WCOMB,
                                              (unsigned short*)(ws + WS_G));
    k3_attn<<<dim3(32, BATCH), 256, 0, stream>>>(h, pos,
                                                 (const unsigned short*)(ws + WS_G),
                                                 ws + WS_SMP);
    k4_final<<<4, 256, 0, stream>>>(ws + WS_SMP, out);
  }
}

// Round 4
// 395.518 us; speedup vs baseline: 1.1201x; 1.1201x over previous
//
#include <hip/hip_runtime.h>
#include <hip/hip_bf16.h>

#define BATCH 32
#define NN 4096
#define KK 32

typedef __attribute__((ext_vector_type(8))) short bf16x8;
typedef __attribute__((ext_vector_type(4))) float f32x4;

// ws float offsets.  SMP (written by K4) overlaps PART/WCOMB/KP, all dead by then.
#define WS_PART   0          // 32*16*256 = 131072
#define WS_WCOMB  131072     // 65536
#define WS_KP     196608     // 262144 (ends 458752)
#define WS_SMP    0          // 5*131072 = 655360 (K4 only)
#define WS_G      655360     // 131072 floats = 262144 bf16
#define WS_CNT    786432     // 33 ints: [0..31] per-b attn counters, [32] LN counter

__device__ __forceinline__ unsigned short f2bf(float x) {
  unsigned int u = __float_as_uint(x);
  u += 0x7fffu + ((u >> 16) & 1u);   // RTNE
  return (unsigned short)(u >> 16);
}

__device__ __forceinline__ unsigned int pk2(float lo, float hi) {
  union { __hip_bfloat162 b; unsigned int u; } c;
  c.b = __float22bfloat162_rn(float2{lo, hi});   // v_cvt_pk_bf16_f32
  return c.u;
}

// ---------------- K1: zero out + counters, colsum partials, wcomb ----------------
__global__ __launch_bounds__(256, 4) void k1_sum_wcomb(
    const float* __restrict__ h, const float* __restrict__ Wsrc,
    const float* __restrict__ Wdst, float* __restrict__ ws,
    float4* __restrict__ out4, int n4) {
  __shared__ float4 sm[256];
  int bk = blockIdx.x, t = threadIdx.x;
  int zi = bk * 256 + t;
  if (zi < n4) out4[zi] = float4{0.f, 0.f, 0.f, 0.f};
  if (bk == 767 && t < 33) ((int*)(ws + WS_CNT))[t] = 0;
  if (bk < 512) {
    // column partial sums: block (b, p) sums rows p*256..p*256+255 of h[b]
    int b = bk >> 4, p = bk & 15;
    int c4 = t & 63, rg = t >> 6;
    const float4* hp = (const float4*)h + (((size_t)(b * NN + p * 256)) << 6) + c4;
    float4 acc = {0.f, 0.f, 0.f, 0.f};
    for (int r = rg; r < 256; r += 4) {
      float4 v = hp[(size_t)r << 6];
      acc.x += v.x; acc.y += v.y; acc.z += v.z; acc.w += v.w;
    }
    sm[t] = acc;
    __syncthreads();
    if (t < 64) {
      float4 a = sm[t], b2 = sm[t + 64], c = sm[t + 128], d = sm[t + 192];
      float4 tot = {a.x + b2.x + c.x + d.x, a.y + b2.y + c.y + d.y,
                    a.z + b2.z + c.z + d.z, a.w + b2.w + c.w + d.w};
      ((float4*)(ws + WS_PART))[(size_t)(b * 16 + p) * 64 + t] = tot;
    }
  } else {
    // wcomb[dp][d] = sum_e Wdst[e][dp] * Wsrc[e][d]  (Wdst read is wave-uniform -> s_load)
    int dp = bk - 512;
    float acc = 0.f;
#pragma unroll 8
    for (int e = 0; e < 256; e++) acc += Wdst[e * 256 + dp] * Wsrc[e * 256 + t];
    ws[WS_WCOMB + dp * 256 + t] = acc;
  }
}

// ---------------- K2: means + kp (j-split) + last-block LayerNorm ----------------
__global__ __launch_bounds__(256, 2) void k2_kp_ln(
    const float* __restrict__ Wkp, const float* __restrict__ bkp,
    const float* __restrict__ gamma, const float* __restrict__ beta,
    float* __restrict__ ws) {
  __shared__ float meanLds[32 * 256];   // 32 KB
  __shared__ int lastFlag;
  int bk = blockIdx.x, t = threadIdx.x;   // 64 blocks
  // redundant means reduce (512 KB partials, coalesced)
  for (int idx = t; idx < 8192; idx += 256) {
    int b = idx >> 8, d = idx & 255;
    float s = 0.f;
#pragma unroll
    for (int p = 0; p < 16; p++) s += ws[WS_PART + (size_t)(b * 16 + p) * 256 + d];
    meanLds[idx] = s * (1.0f / NN);
  }
  __syncthreads();
  // kp[b][j] = silu(mean[b] . Wkp[j] + bkp[j]); j = bk*128 + (t&127); 2 threads/j (16 b each)
  int j = bk * 128 + (t & 127);
  int bh = (t >> 7) * 16;
  const float4* wrow = (const float4*)(Wkp + (size_t)j * 256);
  float acc[16];
#pragma unroll
  for (int i = 0; i < 16; i++) acc[i] = 0.f;
  for (int d4 = 0; d4 < 64; d4++) {
    float4 wv = wrow[d4];
#pragma unroll
    for (int i = 0; i < 16; i++) {
      float4 m = ((const float4*)meanLds)[(bh + i) * 64 + d4];  // wave-uniform broadcast
      acc[i] += wv.x * m.x + wv.y * m.y + wv.z * m.z + wv.w * m.w;
    }
  }
  float bb = bkp[j];
#pragma unroll
  for (int i = 0; i < 16; i++) {
    float x = acc[i] + bb;
    ws[WS_KP + (size_t)(bh + i) * 8192 + j] = x / (1.0f + __expf(-x));
  }
  // last-block-done LayerNorm over all 32 rows
  __threadfence();
  __syncthreads();
  if (t == 0) {
    int old = atomicAdd((int*)(ws + WS_CNT) + 32, 1);
    lastFlag = (old == 63);
  }
  __syncthreads();
  if (!lastFlag) return;
  __threadfence();
  int b = t >> 3, sub = t & 7;          // 8 threads per batch row
  float* kp = ws + WS_KP + (size_t)b * 8192;
  float s = 0.f, sq = 0.f;
  for (int idx = sub; idx < 2048; idx += 8) {
    float4 v = ((const float4*)kp)[idx];
    s += v.x + v.y + v.z + v.w;
    sq += v.x * v.x + v.y * v.y + v.z * v.z + v.w * v.w;
  }
#pragma unroll
  for (int o = 1; o < 8; o <<= 1) { s += __shfl_xor(s, o); sq += __shfl_xor(sq, o); }
  float mu = s * (1.0f / 8192.0f);
  float var = fmaxf(sq * (1.0f / 8192.0f) - mu * mu, 0.f);
  float rs = rsqrtf(var + 1e-5f);
  for (int idx = sub; idx < 2048; idx += 8) {
    float4 v = ((const float4*)kp)[idx];
    float4 g4 = ((const float4*)gamma)[idx];
    float4 b4 = ((const float4*)beta)[idx];
    v.x = (v.x - mu) * rs * g4.x + b4.x;
    v.y = (v.y - mu) * rs * g4.y + b4.y;
    v.z = (v.z - mu) * rs * g4.z + b4.z;
    v.w = (v.w - mu) * rs * g4.w + b4.w;
    ((float4*)kp)[idx] = v;
  }
}

// ---------------- K3: g = (kpn @ wcomb) / 16 -> bf16 ----------------
__global__ void k3_g(const float* __restrict__ ws_in, float* __restrict__ ws) {
  int dc = blockIdx.x, b = blockIdx.y, t = threadIdx.x;
  int d = dc * 64 + (t & 63);
  int kb = t >> 6;
  const float* kpn = ws_in + WS_KP;
  const float* wcomb = ws_in + WS_WCOMB;
  unsigned short* g = (unsigned short*)(ws + WS_G);
  float acc[8] = {0.f, 0.f, 0.f, 0.f, 0.f, 0.f, 0.f, 0.f};
  for (int dp4 = 0; dp4 < 64; dp4++) {
    float w0 = wcomb[(dp4 * 4 + 0) * 256 + d];
    float w1 = wcomb[(dp4 * 4 + 1) * 256 + d];
    float w2 = wcomb[(dp4 * 4 + 2) * 256 + d];
    float w3 = wcomb[(dp4 * 4 + 3) * 256 + d];
#pragma unroll
    for (int i = 0; i < 8; i++) {
      int k = kb + i * 4;
      float4 kv = ((const float4*)(kpn + (size_t)b * 8192 + k * 256))[dp4];  // uniform
      acc[i] += kv.x * w0 + kv.y * w1 + kv.z * w2 + kv.w * w3;
    }
  }
#pragma unroll
  for (int i = 0; i < 8; i++) {
    int k = kb + i * 4;
    g[(size_t)(b * KK + k) * 256 + d] = f2bf(acc[i] * 0.0625f);  // fold 1/sqrt(256)
  }
}

// ---------------- K4: attention partials + last-block final ----------------
__global__ __launch_bounds__(256, 4) void k4_attn(
    const float* __restrict__ h, const float* __restrict__ pos,
    const unsigned short* __restrict__ gbuf, float* __restrict__ ws,
    float* __restrict__ out) {
  __shared__ __align__(16) unsigned short glds[8192];  // 16 KB, XOR-swizzled
  __shared__ int lastFlag;
  const int s = blockIdx.x, b = blockIdx.y, t = threadIdx.x;
  const int lane = t & 63, w = t >> 6;
  const int l15 = lane & 15, l4 = lane >> 4;
  const float LOG2E = 1.4426950408889634f;
  {
    const float4* gsrc = (const float4*)(gbuf + (size_t)b * 8192);
    float4* gdst = (float4*)glds;
    for (int i = t; i < 1024; i += 256) {
      int k = i >> 5, c = i & 31;
      gdst[k * 32 + (c ^ (k & 7))] = gsrc[i];   // T2 swizzle, 2-way max on read
    }
  }
  __syncthreads();
  const bf16x8* gl = (const bf16x8*)glds;
  const int sw = l15 & 7;

  float m0 = -3.0e38f, m1 = -3.0e38f;
  float L0 = 0.f, L1 = 0.f;
  float P0x = 0.f, P0y = 0.f, P0z = 0.f, P1x = 0.f, P1y = 0.f, P1z = 0.f;

  for (int tile = 0; tile < 2; tile++) {
    int nbase = s * 128 + tile * 64 + w * 16;
    const float4* hp = (const float4*)(h + ((size_t)(b * NN + nbase + l15) << 8));
    int co = l4 * 2;
    f32x4 acc0 = {0.f, 0.f, 0.f, 0.f}, acc1 = {0.f, 0.f, 0.f, 0.f};
#pragma unroll
    for (int kd = 0; kd < 8; kd++) {
      float4 v0 = hp[kd * 8 + co];
      float4 v1 = hp[kd * 8 + co + 1];
      union { unsigned int u[4]; bf16x8 v; } au;
      au.u[0] = pk2(v0.x, v0.y); au.u[1] = pk2(v0.z, v0.w);
      au.u[2] = pk2(v1.x, v1.y); au.u[3] = pk2(v1.z, v1.w);
      int cidx = (kd * 4 + l4) ^ sw;
      bf16x8 g0 = gl[l15 * 32 + cidx];
      bf16x8 g1 = gl[(16 + l15) * 32 + cidx];
      acc0 = __builtin_amdgcn_mfma_f32_16x16x32_bf16(au.v, g0, acc0, 0, 0, 0);
      acc1 = __builtin_amdgcn_mfma_f32_16x16x32_bf16(au.v, g1, acc1, 0, 0, 0);
    }
    float px[4], py[4], pz[4];
#pragma unroll
    for (int j = 0; j < 4; j++) {
      const float* pp = pos + (size_t)(b * NN + nbase + l4 * 4 + j) * 3;
      px[j] = pp[0]; py[j] = pp[1]; pz[j] = pp[2];
    }
    {
      float tm = fmaxf(fmaxf(acc0[0], acc0[1]), fmaxf(acc0[2], acc0[3]));
      tm = fmaxf(tm, __shfl_xor(tm, 16));
      tm = fmaxf(tm, __shfl_xor(tm, 32));
      float mn = fmaxf(m0, tm);
      float corr = exp2f((m0 - mn) * LOG2E);
      float e0 = exp2f((acc0[0] - mn) * LOG2E);
      float e1 = exp2f((acc0[1] - mn) * LOG2E);
      float e2 = exp2f((acc0[2] - mn) * LOG2E);
      float e3 = exp2f((acc0[3] - mn) * LOG2E);
      float se = e0 + e1 + e2 + e3;
      float sx = e0 * px[0] + e1 * px[1] + e2 * px[2] + e3 * px[3];
      float sy = e0 * py[0] + e1 * py[1] + e2 * py[2] + e3 * py[3];
      float sz = e0 * pz[0] + e1 * pz[1] + e2 * pz[2] + e3 * pz[3];
      se += __shfl_xor(se, 16); se += __shfl_xor(se, 32);
      sx += __shfl_xor(sx, 16); sx += __shfl_xor(sx, 32);
      sy += __shfl_xor(sy, 16); sy += __shfl_xor(sy, 32);
      sz += __shfl_xor(sz, 16); sz += __shfl_xor(sz, 32);
      L0 = L0 * corr + se; P0x = P0x * corr + sx;
      P0y = P0y * corr + sy; P0z = P0z * corr + sz; m0 = mn;
    }
    {
      float tm = fmaxf(fmaxf(acc1[0], acc1[1]), fmaxf(acc1[2], acc1[3]));
      tm = fmaxf(tm, __shfl_xor(tm, 16));
      tm = fmaxf(tm, __shfl_xor(tm, 32));
      float mn = fmaxf(m1, tm);
      float corr = exp2f((m1 - mn) * LOG2E);
      float e0 = exp2f((acc1[0] - mn) * LOG2E);
      float e1 = exp2f((acc1[1] - mn) * LOG2E);
      float e2 = exp2f((acc1[2] - mn) * LOG2E);
      float e3 = exp2f((acc1[3] - mn) * LOG2E);
      float se = e0 + e1 + e2 + e3;
      float sx = e0 * px[0] + e1 * px[1] + e2 * px[2] + e3 * px[3];
      float sy = e0 * py[0] + e1 * py[1] + e2 * py[2] + e3 * py[3];
      float sz = e0 * pz[0] + e1 * pz[1] + e2 * pz[2] + e3 * pz[3];
      se += __shfl_xor(se, 16); se += __shfl_xor(se, 32);
      sx += __shfl_xor(sx, 16); sx += __shfl_xor(sx, 32);
      sy += __shfl_xor(sy, 16); sy += __shfl_xor(sy, 32);
      sz += __shfl_xor(sz, 16); sz += __shfl_xor(sz, 32);
      L1 = L1 * corr + se; P1x = P1x * corr + sx;
      P1y = P1y * corr + sy; P1z = P1z * corr + sz; m1 = mn;
    }
  }
  if (lane < 32) {
    int kt = lane >> 4;
    float mv = kt ? m1 : m0;
    float lv = kt ? L1 : L0;
    float pxv = kt ? P1x : P0x;
    float pyv = kt ? P1y : P0y;
    float pzv = kt ? P1z : P0z;
    size_t base = ((size_t)(b * KK + lane)) * 128 + s * 4 + w;
    ws[WS_SMP + base] = mv;
    ws[WS_SMP + 131072 + base] = lv;
    ws[WS_SMP + 262144 + base] = pxv;
    ws[WS_SMP + 393216 + base] = pyv;
    ws[WS_SMP + 524288 + base] = pzv;
  }
  // last-block-done final combine for this b
  __threadfence();
  __syncthreads();
  if (t == 0) {
    int old = atomicAdd((int*)(ws + WS_CNT) + b, 1);
    lastFlag = (old == 31);
  }
  __syncthreads();
  if (!lastFlag) return;
  __threadfence();
  const float* P = ws + WS_SMP;
  int k = t >> 3, sub = t & 7;     // 8 threads per keypoint
  size_t base = ((size_t)(b * KK + k)) * 128;
  float M = -3.0e38f;
  for (int j = sub; j < 128; j += 8) M = fmaxf(M, P[base + j]);
#pragma unroll
  for (int o = 1; o < 8; o <<= 1) M = fmaxf(M, __shfl_xor(M, o));
  float L = 0.f, X = 0.f, Y = 0.f, Z = 0.f;
  for (int j = sub; j < 128; j += 8) {
    float f = exp2f((P[base + j] - M) * LOG2E);
    L += P[131072 + base + j] * f;
    X += P[262144 + base + j] * f;
    Y += P[393216 + base + j] * f;
    Z += P[524288 + base + j] * f;
  }
#pragma unroll
  for (int o = 1; o < 8; o <<= 1) {
    L += __shfl_xor(L, o); X += __shfl_xor(X, o);
    Y += __shfl_xor(Y, o); Z += __shfl_xor(Z, o);
  }
  if (sub == 0) {
    float inv = 1.0f / L;
    out[(b * KK + k) * 3 + 0] = X * inv;
    out[(b * KK + k) * 3 + 1] = Y * inv;
    out[(b * KK + k) * 3 + 2] = Z * inv;
  }
}

extern "C" void kernel_launch(void* const* d_in, const int* in_sizes, int n_in,
                              void* d_out, int out_size, void* d_ws, size_t ws_size,
                              hipStream_t stream) {
  const float* h     = (const float*)d_in[0];
  const float* pos   = (const float*)d_in[1];
  const float* Wsrc  = (const float*)d_in[2];
  const float* Wdst  = (const float*)d_in[3];
  const float* Wkp   = (const float*)d_in[4];
  const float* bkp   = (const float*)d_in[5];
  const float* gamma = (const float*)d_in[6];
  const float* beta  = (const float*)d_in[7];
  float* out = (float*)d_out;
  float* ws  = (float*)d_ws;

  k1_sum_wcomb<<<768, 256, 0, stream>>>(h, Wsrc, Wdst, ws, (float4*)d_out,
                                        out_size / 4);
  k2_kp_ln<<<64, 256, 0, stream>>>(Wkp, bkp, gamma, beta, ws);
  k3_g<<<dim3(4, BATCH), 256, 0, stream>>>(ws, ws);
  k4_attn<<<dim3(32, BATCH), 256, 0, stream>>>(h, pos,
                                               (const unsigned short*)(ws + WS_G),
                                               ws, out);
}

// Round 5
// 144.768 us; speedup vs baseline: 3.0602x; 2.7321x over previous
//
#include <hip/hip_runtime.h>
#include <hip/hip_bf16.h>

#define BATCH 32
#define NN 4096
#define KK 32

typedef __attribute__((ext_vector_type(8))) short bf16x8;
typedef __attribute__((ext_vector_type(4))) float f32x4;

// ws float offsets.  SMP (written by K4) overlaps PART/WCOMB/KP, all dead by then.
#define WS_PART   0          // 32*16*256 = 131072
#define WS_WCOMB  131072     // 65536
#define WS_KP     196608     // 262144 (ends 458752)
#define WS_SMP    0          // 5*131072 = 655360 (K4 only)
#define WS_G      655360     // 131072 floats = 262144 bf16

__device__ __forceinline__ unsigned short f2bf(float x) {
  unsigned int u = __float_as_uint(x);
  u += 0x7fffu + ((u >> 16) & 1u);   // RTNE
  return (unsigned short)(u >> 16);
}

__device__ __forceinline__ unsigned int pk2(float lo, float hi) {
  union { __hip_bfloat162 b; unsigned int u; } c;
  c.b = __float22bfloat162_rn(float2{lo, hi});   // v_cvt_pk_bf16_f32
  return c.u;
}

// ---------------- K1: zero out, colsum partials, wcomb ----------------
__global__ __launch_bounds__(256, 4) void k1_sum_wcomb(
    const float* __restrict__ h, const float* __restrict__ Wsrc,
    const float* __restrict__ Wdst, float* __restrict__ ws,
    float4* __restrict__ out4, int n4) {
  __shared__ float4 sm[256];
  int bk = blockIdx.x, t = threadIdx.x;
  int zi = bk * 256 + t;
  if (zi < n4) out4[zi] = float4{0.f, 0.f, 0.f, 0.f};
  if (bk < 512) {
    // column partial sums: block (b, p) sums rows p*256..p*256+255 of h[b]
    int b = bk >> 4, p = bk & 15;
    int c4 = t & 63, rg = t >> 6;
    const float4* hp = (const float4*)h + (((size_t)(b * NN + p * 256)) << 6) + c4;
    float4 acc = {0.f, 0.f, 0.f, 0.f};
    for (int r = rg; r < 256; r += 4) {
      float4 v = hp[(size_t)r << 6];
      acc.x += v.x; acc.y += v.y; acc.z += v.z; acc.w += v.w;
    }
    sm[t] = acc;
    __syncthreads();
    if (t < 64) {
      float4 a = sm[t], b2 = sm[t + 64], c = sm[t + 128], d = sm[t + 192];
      float4 tot = {a.x + b2.x + c.x + d.x, a.y + b2.y + c.y + d.y,
                    a.z + b2.z + c.z + d.z, a.w + b2.w + c.w + d.w};
      ((float4*)(ws + WS_PART))[(size_t)(b * 16 + p) * 64 + t] = tot;
    }
  } else {
    // wcomb[dp][d] = sum_e Wdst[e][dp] * Wsrc[e][d]
    int dp = bk - 512;
    float acc = 0.f;
#pragma unroll 8
    for (int e = 0; e < 256; e++) acc += Wdst[e * 256 + dp] * Wsrc[e * 256 + t];
    ws[WS_WCOMB + dp * 256 + t] = acc;
  }
}

// ---------------- K2: means + kp = silu(mean @ Wkp^T + b), j-split ----------------
__global__ __launch_bounds__(256, 2) void k2_kp(
    const float* __restrict__ Wkp, const float* __restrict__ bkp,
    float* __restrict__ ws) {
  __shared__ float meanLds[32 * 256];   // 32 KB
  int bk = blockIdx.x, t = threadIdx.x;   // 64 blocks
  // redundant means reduce (512 KB partials, L2-shared across blocks)
  for (int idx = t; idx < 8192; idx += 256) {
    int b = idx >> 8, d = idx & 255;
    float s = 0.f;
#pragma unroll
    for (int p = 0; p < 16; p++) s += ws[WS_PART + (size_t)(b * 16 + p) * 256 + d];
    meanLds[idx] = s * (1.0f / NN);
  }
  __syncthreads();
  // j = bk*128 + (t&127); 2 threads per j, 16 batches each
  int j = bk * 128 + (t & 127);
  int bh = (t >> 7) * 16;
  const float4* wrow = (const float4*)(Wkp + (size_t)j * 256);
  float acc[16];
#pragma unroll
  for (int i = 0; i < 16; i++) acc[i] = 0.f;
  for (int d4 = 0; d4 < 64; d4++) {
    float4 wv = wrow[d4];
#pragma unroll
    for (int i = 0; i < 16; i++) {
      float4 m = ((const float4*)meanLds)[(bh + i) * 64 + d4];
      acc[i] += wv.x * m.x + wv.y * m.y + wv.z * m.z + wv.w * m.w;
    }
  }
  float bb = bkp[j];
#pragma unroll
  for (int i = 0; i < 16; i++) {
    float x = acc[i] + bb;
    ws[WS_KP + (size_t)(bh + i) * 8192 + j] = x / (1.0f + __expf(-x));
  }
}

// ---------------- K2b: LayerNorm over 8192, in place (one block per b) ----------------
__global__ void k2b_ln(float* __restrict__ ws, const float* __restrict__ gamma,
                       const float* __restrict__ beta) {
  __shared__ float red[8];
  int b = blockIdx.x, t = threadIdx.x;
  float* kp = ws + WS_KP + (size_t)b * 8192;
  float4 v[8];
  float s = 0.f, sq = 0.f;
#pragma unroll
  for (int i = 0; i < 8; i++) {
    v[i] = ((const float4*)kp)[t + i * 256];
    s += v[i].x + v[i].y + v[i].z + v[i].w;
    sq += v[i].x * v[i].x + v[i].y * v[i].y + v[i].z * v[i].z + v[i].w * v[i].w;
  }
#pragma unroll
  for (int o = 1; o < 64; o <<= 1) { s += __shfl_xor(s, o); sq += __shfl_xor(sq, o); }
  int w = t >> 6, lane = t & 63;
  if (lane == 0) { red[w] = s; red[4 + w] = sq; }
  __syncthreads();
  float S = red[0] + red[1] + red[2] + red[3];
  float SQ = red[4] + red[5] + red[6] + red[7];
  float mu = S * (1.0f / 8192.0f);
  float var = fmaxf(SQ * (1.0f / 8192.0f) - mu * mu, 0.f);
  float rs = rsqrtf(var + 1e-5f);
#pragma unroll
  for (int i = 0; i < 8; i++) {
    float4 g4 = ((const float4*)gamma)[t + i * 256];
    float4 b4 = ((const float4*)beta)[t + i * 256];
    float4 o;
    o.x = (v[i].x - mu) * rs * g4.x + b4.x;
    o.y = (v[i].y - mu) * rs * g4.y + b4.y;
    o.z = (v[i].z - mu) * rs * g4.z + b4.z;
    o.w = (v[i].w - mu) * rs * g4.w + b4.w;
    ((float4*)kp)[t + i * 256] = o;
  }
}

// ---------------- K3: g = (kpn @ wcomb) / 16 -> bf16 ----------------
__global__ void k3_g(const float* __restrict__ ws_in, float* __restrict__ ws) {
  int dc = blockIdx.x, b = blockIdx.y, t = threadIdx.x;
  int d = dc * 64 + (t & 63);
  int kb = t >> 6;
  const float* kpn = ws_in + WS_KP;
  const float* wcomb = ws_in + WS_WCOMB;
  unsigned short* g = (unsigned short*)(ws + WS_G);
  float acc[8] = {0.f, 0.f, 0.f, 0.f, 0.f, 0.f, 0.f, 0.f};
  for (int dp4 = 0; dp4 < 64; dp4++) {
    float w0 = wcomb[(dp4 * 4 + 0) * 256 + d];
    float w1 = wcomb[(dp4 * 4 + 1) * 256 + d];
    float w2 = wcomb[(dp4 * 4 + 2) * 256 + d];
    float w3 = wcomb[(dp4 * 4 + 3) * 256 + d];
#pragma unroll
    for (int i = 0; i < 8; i++) {
      int k = kb + i * 4;
      float4 kv = ((const float4*)(kpn + (size_t)b * 8192 + k * 256))[dp4];
      acc[i] += kv.x * w0 + kv.y * w1 + kv.z * w2 + kv.w * w3;
    }
  }
#pragma unroll
  for (int i = 0; i < 8; i++) {
    int k = kb + i * 4;
    g[(size_t)(b * KK + k) * 256 + d] = f2bf(acc[i] * 0.0625f);  // fold 1/sqrt(256)
  }
}

// ---------------- K4: attention partials (no fences, no atomics) ----------------
__global__ __launch_bounds__(256, 4) void k4_attn(
    const float* __restrict__ h, const float* __restrict__ pos,
    const unsigned short* __restrict__ gbuf, float* __restrict__ ws) {
  __shared__ __align__(16) unsigned short glds[8192];  // 16 KB, XOR-swizzled
  const int s = blockIdx.x, b = blockIdx.y, t = threadIdx.x;
  const int lane = t & 63, w = t >> 6;
  const int l15 = lane & 15, l4 = lane >> 4;
  const float LOG2E = 1.4426950408889634f;
  {
    const float4* gsrc = (const float4*)(gbuf + (size_t)b * 8192);
    float4* gdst = (float4*)glds;
    for (int i = t; i < 1024; i += 256) {
      int k = i >> 5, c = i & 31;
      gdst[k * 32 + (c ^ (k & 7))] = gsrc[i];   // T2 swizzle
    }
  }
  __syncthreads();
  const bf16x8* gl = (const bf16x8*)glds;
  const int sw = l15 & 7;

  float m0 = -3.0e38f, m1 = -3.0e38f;
  float L0 = 0.f, L1 = 0.f;
  float P0x = 0.f, P0y = 0.f, P0z = 0.f, P1x = 0.f, P1y = 0.f, P1z = 0.f;

  for (int tile = 0; tile < 2; tile++) {
    int nbase = s * 128 + tile * 64 + w * 16;
    const float4* hp = (const float4*)(h + ((size_t)(b * NN + nbase + l15) << 8));
    int co = l4 * 2;
    f32x4 acc0 = {0.f, 0.f, 0.f, 0.f}, acc1 = {0.f, 0.f, 0.f, 0.f};
#pragma unroll
    for (int kd = 0; kd < 8; kd++) {
      float4 v0 = hp[kd * 8 + co];
      float4 v1 = hp[kd * 8 + co + 1];
      union { unsigned int u[4]; bf16x8 v; } au;
      au.u[0] = pk2(v0.x, v0.y); au.u[1] = pk2(v0.z, v0.w);
      au.u[2] = pk2(v1.x, v1.y); au.u[3] = pk2(v1.z, v1.w);
      int cidx = (kd * 4 + l4) ^ sw;
      bf16x8 g0 = gl[l15 * 32 + cidx];
      bf16x8 g1 = gl[(16 + l15) * 32 + cidx];
      acc0 = __builtin_amdgcn_mfma_f32_16x16x32_bf16(au.v, g0, acc0, 0, 0, 0);
      acc1 = __builtin_amdgcn_mfma_f32_16x16x32_bf16(au.v, g1, acc1, 0, 0, 0);
    }
    float px[4], py[4], pz[4];
#pragma unroll
    for (int j = 0; j < 4; j++) {
      const float* pp = pos + (size_t)(b * NN + nbase + l4 * 4 + j) * 3;
      px[j] = pp[0]; py[j] = pp[1]; pz[j] = pp[2];
    }
    {
      float tm = fmaxf(fmaxf(acc0[0], acc0[1]), fmaxf(acc0[2], acc0[3]));
      tm = fmaxf(tm, __shfl_xor(tm, 16));
      tm = fmaxf(tm, __shfl_xor(tm, 32));
      float mn = fmaxf(m0, tm);
      float corr = exp2f((m0 - mn) * LOG2E);
      float e0 = exp2f((acc0[0] - mn) * LOG2E);
      float e1 = exp2f((acc0[1] - mn) * LOG2E);
      float e2 = exp2f((acc0[2] - mn) * LOG2E);
      float e3 = exp2f((acc0[3] - mn) * LOG2E);
      float se = e0 + e1 + e2 + e3;
      float sx = e0 * px[0] + e1 * px[1] + e2 * px[2] + e3 * px[3];
      float sy = e0 * py[0] + e1 * py[1] + e2 * py[2] + e3 * py[3];
      float sz = e0 * pz[0] + e1 * pz[1] + e2 * pz[2] + e3 * pz[3];
      se += __shfl_xor(se, 16); se += __shfl_xor(se, 32);
      sx += __shfl_xor(sx, 16); sx += __shfl_xor(sx, 32);
      sy += __shfl_xor(sy, 16); sy += __shfl_xor(sy, 32);
      sz += __shfl_xor(sz, 16); sz += __shfl_xor(sz, 32);
      L0 = L0 * corr + se; P0x = P0x * corr + sx;
      P0y = P0y * corr + sy; P0z = P0z * corr + sz; m0 = mn;
    }
    {
      float tm = fmaxf(fmaxf(acc1[0], acc1[1]), fmaxf(acc1[2], acc1[3]));
      tm = fmaxf(tm, __shfl_xor(tm, 16));
      tm = fmaxf(tm, __shfl_xor(tm, 32));
      float mn = fmaxf(m1, tm);
      float corr = exp2f((m1 - mn) * LOG2E);
      float e0 = exp2f((acc1[0] - mn) * LOG2E);
      float e1 = exp2f((acc1[1] - mn) * LOG2E);
      float e2 = exp2f((acc1[2] - mn) * LOG2E);
      float e3 = exp2f((acc1[3] - mn) * LOG2E);
      float se = e0 + e1 + e2 + e3;
      float sx = e0 * px[0] + e1 * px[1] + e2 * px[2] + e3 * px[3];
      float sy = e0 * py[0] + e1 * py[1] + e2 * py[2] + e3 * py[3];
      float sz = e0 * pz[0] + e1 * pz[1] + e2 * pz[2] + e3 * pz[3];
      se += __shfl_xor(se, 16); se += __shfl_xor(se, 32);
      sx += __shfl_xor(sx, 16); sx += __shfl_xor(sx, 32);
      sy += __shfl_xor(sy, 16); sy += __shfl_xor(sy, 32);
      sz += __shfl_xor(sz, 16); sz += __shfl_xor(sz, 32);
      L1 = L1 * corr + se; P1x = P1x * corr + sx;
      P1y = P1y * corr + sy; P1z = P1z * corr + sz; m1 = mn;
    }
  }
  if (lane < 32) {
    int kt = lane >> 4;
    float mv = kt ? m1 : m0;
    float lv = kt ? L1 : L0;
    float pxv = kt ? P1x : P0x;
    float pyv = kt ? P1y : P0y;
    float pzv = kt ? P1z : P0z;
    size_t base = ((size_t)(b * KK + lane)) * 128 + s * 4 + w;
    ws[WS_SMP + base] = mv;
    ws[WS_SMP + 131072 + base] = lv;
    ws[WS_SMP + 262144 + base] = pxv;
    ws[WS_SMP + 393216 + base] = pyv;
    ws[WS_SMP + 524288 + base] = pzv;
  }
}

// ---------------- K5: combine partials -> kp_pos ----------------
__global__ void k5_final(const float* __restrict__ smp, float* __restrict__ out) {
  int id = blockIdx.x * 256 + threadIdx.x;
  if (id >= BATCH * KK) return;
  const float LOG2E = 1.4426950408889634f;
  size_t base = (size_t)id * 128;
  float M = -3.0e38f;
  for (int j = 0; j < 128; j++) M = fmaxf(M, smp[base + j]);
  float L = 0.f, X = 0.f, Y = 0.f, Z = 0.f;
  for (int j = 0; j < 128; j++) {
    float f = exp2f((smp[base + j] - M) * LOG2E);
    L += smp[131072 + base + j] * f;
    X += smp[262144 + base + j] * f;
    Y += smp[393216 + base + j] * f;
    Z += smp[524288 + base + j] * f;
  }
  float inv = 1.0f / L;
  out[id * 3 + 0] = X * inv;
  out[id * 3 + 1] = Y * inv;
  out[id * 3 + 2] = Z * inv;
}

extern "C" void kernel_launch(void* const* d_in, const int* in_sizes, int n_in,
                              void* d_out, int out_size, void* d_ws, size_t ws_size,
                              hipStream_t stream) {
  const float* h     = (const float*)d_in[0];
  const float* pos   = (const float*)d_in[1];
  const float* Wsrc  = (const float*)d_in[2];
  const float* Wdst  = (const float*)d_in[3];
  const float* Wkp   = (const float*)d_in[4];
  const float* bkp   = (const float*)d_in[5];
  const float* gamma = (const float*)d_in[6];
  const float* beta  = (const float*)d_in[7];
  float* out = (float*)d_out;
  float* ws  = (float*)d_ws;

  k1_sum_wcomb<<<768, 256, 0, stream>>>(h, Wsrc, Wdst, ws, (float4*)d_out,
                                        out_size / 4);
  k2_kp<<<64, 256, 0, stream>>>(Wkp, bkp, ws);
  k2b_ln<<<BATCH, 256, 0, stream>>>(ws, gamma, beta);
  k3_g<<<dim3(4, BATCH), 256, 0, stream>>>(ws, ws);
  k4_attn<<<dim3(32, BATCH), 256, 0, stream>>>(h, pos,
                                               (const unsigned short*)(ws + WS_G),
                                               ws);
  k5_final<<<4, 256, 0, stream>>>(ws + WS_SMP, out);
}